// Round 6
// baseline (373.744 us; speedup 1.0000x reference)
//
#include <hip/hip_runtime.h>

// ---------------------------------------------------------------------------
// TripletLossWithHardMining  (B=4096, D=1024, fp32 in, fp32 scalar out)
//
//  K1 row_stats : wave-per-row; per-row constants; d_ap, d_an_row; bf16
//                 copies of a,p,n; init hard slots.
//  K2 gemm_mask : R10 = R0 (best, 96.7us) with A REMOVED FROM LDS.
//                 Theory: all five prior variants pinned at MfmaUtil 24-29%
//                 because LDS-pipe cycles/FLOP were identical (24 ds_read_b128
//                 + 12 g2l per wave-K-tile ~ 1630 cyc/block-K-tile vs 620 cyc
//                 MFMA demand -> LDS-pipe-bound at ~27%). A-fragments load
//                 global->VGPR directly (lane reads row l&15, 16B at k-chunk
//                 (half*4+quad)*8; 2 waves/block share lines via L1, 32
//                 j-blocks share A-panels via L2). LDS now stages only N,P:
//                 reads 24->16, writes 12->8 per wave-K-tile (-33% LDS
//                 cycles); LDS 48->32 KB -> 3 blocks/CU (launch_bounds 256,3).
//                 Everything else identical to R0: fused N+P epilogue,
//                 global_load_lds(16B) + XOR chunk swizzle for N/P, BK=64,
//                 2-barrier K-loop.
//  K3 finalize  : d_an = mean(hard_n), d_pp = mean(hard_p, inf->0),
//                 loss = mean(relu(d_ap - 0.5*d_pp - 0.5*d_an + 1)).
//
//  Dead-ends (MfmaUtil pinned 24-29 across ALL -> LDS-traffic bound):
//   R4 barrier-free per-wave vmcnt(4):        184us, 15%
//   R5 fused 256x128 8-phase + vmcnt(0)/tile: 104us, 27%
//   R6 fused 256x128 4-phase counted:         107us, 26%
//   R7 unfused 128^2 2-barrier, 3 blk/CU:     104us, 27%
//   R9 unfused 256^2 k-half counted vmcnt(4): 117us, 24%
// ---------------------------------------------------------------------------

#define NB 4096
#define DIM 1024
#define EPSF 1e-6f
#define D_EPS2 (1024.0f * 1e-6f * 1e-6f)

#define BM 128           // block tile (rows and cols)
#define BK 64            // k-tile (bf16 elems) -> 128 B rows, unpadded

typedef __bf16  bf16x8 __attribute__((ext_vector_type(8)));
typedef float   f32x4  __attribute__((ext_vector_type(4)));

__device__ __forceinline__ unsigned short f2bf(float x) {
    unsigned u = __float_as_uint(x);
    u += 0x7FFFu + ((u >> 16) & 1u);   // round-to-nearest-even
    return (unsigned short)(u >> 16);
}

// async 16B/lane global->LDS; lds base wave-uniform, data lands at base+lane*16
__device__ __forceinline__ void g2l16(const unsigned short* g, unsigned short* l) {
    __builtin_amdgcn_global_load_lds(
        (const __attribute__((address_space(1))) unsigned int*)g,
        (__attribute__((address_space(3))) unsigned int*)l, 16, 0, 0);
}

// stats layout (NB-float slots):
// 0: base_a[i] = |a_i|^2 + 2e*sum_a + D*e^2
// 1: cn[j]     = |n_j|^2 - 2e*sum_n
// 2: cp[j]     = |p_j|^2 - 2e*sum_p
// 3: d_ap   4: d_an_row   5: hard_n bits   6: hard_p bits

// wave-per-row: 1024 blocks x 4 waves; lane handles 4 float4 chunks per matrix
__global__ __launch_bounds__(256) void row_stats_kernel(
    const float* __restrict__ a, const float* __restrict__ p,
    const float* __restrict__ n,
    unsigned short* __restrict__ abf, unsigned short* __restrict__ pbf,
    unsigned short* __restrict__ nbf, float* __restrict__ stats)
{
    const int t    = threadIdx.x;
    const int wave = t >> 6, lane = t & 63;
    const int row  = blockIdx.x * 4 + wave;
    const size_t base = (size_t)row * DIM;

    const float4* a4 = (const float4*)(a + base);
    const float4* p4 = (const float4*)(p + base);
    const float4* n4 = (const float4*)(n + base);

    float v[8] = {0,0,0,0,0,0,0,0};   // sa qa sp qp sn qn dap2 dan2
#pragma unroll
    for (int c = 0; c < 4; c++) {
        const int idx = c * 64 + lane;
        const float4 va = a4[idx];
        const float4 vp = p4[idx];
        const float4 vn = n4[idx];
        const float fa[4] = {va.x, va.y, va.z, va.w};
        const float fp[4] = {vp.x, vp.y, vp.z, vp.w};
        const float fn[4] = {vn.x, vn.y, vn.z, vn.w};
#pragma unroll
        for (int e = 0; e < 4; e++) {
            v[0] += fa[e];           v[1] += fa[e] * fa[e];
            v[2] += fp[e];           v[3] += fp[e] * fp[e];
            v[4] += fn[e];           v[5] += fn[e] * fn[e];
            float dp = fa[e] - fp[e] + EPSF;  v[6] += dp * dp;
            float dn = fa[e] - fn[e] + EPSF;  v[7] += dn * dn;
        }
        ushort4 ba, bp, bn;
        ba.x = f2bf(fa[0]); ba.y = f2bf(fa[1]); ba.z = f2bf(fa[2]); ba.w = f2bf(fa[3]);
        bp.x = f2bf(fp[0]); bp.y = f2bf(fp[1]); bp.z = f2bf(fp[2]); bp.w = f2bf(fp[3]);
        bn.x = f2bf(fn[0]); bn.y = f2bf(fn[1]); bn.z = f2bf(fn[2]); bn.w = f2bf(fn[3]);
        ((ushort4*)(abf + base))[idx] = ba;
        ((ushort4*)(pbf + base))[idx] = bp;
        ((ushort4*)(nbf + base))[idx] = bn;
    }

#pragma unroll
    for (int m = 32; m >= 1; m >>= 1)
#pragma unroll
        for (int q = 0; q < 8; q++) v[q] += __shfl_xor(v[q], m);

    if (lane == 0) {
        stats[0 * NB + row] = v[1] + 2.0f * EPSF * v[0] + D_EPS2;  // base_a
        stats[1 * NB + row] = v[5] - 2.0f * EPSF * v[4];           // cn
        stats[2 * NB + row] = v[3] - 2.0f * EPSF * v[2];           // cp
        stats[3 * NB + row] = sqrtf(v[6]);                         // d_ap
        stats[4 * NB + row] = sqrtf(v[7]);                         // d_an_row
        ((unsigned*)stats)[5 * NB + row] = 0u;                     // hard_n
        ((unsigned*)stats)[6 * NB + row] = 0x7f800000u;            // hard_p
    }
}

// grid (32, 32): each block computes both A.N^T and A.P^T for its tile.
// A-fragments come straight from global (L1/L2-served); LDS holds only N, P.
__global__ __launch_bounds__(256, 3) void gemm_mask_kernel(
    const unsigned short* __restrict__ Abf,
    const unsigned short* __restrict__ Nbf,
    const unsigned short* __restrict__ Pbf,
    float* __restrict__ stats)
{
    const int i0 = blockIdx.x * BM;
    const int j0 = blockIdx.y * BM;

    __shared__ unsigned short sN[BM * BK];   // 16 KB
    __shared__ unsigned short sP[BM * BK];   // 16 KB -> 32 KB total

    const int t    = threadIdx.x;
    const int wave = t >> 6, lane = t & 63;
    const int wm   = wave >> 1, wn = wave & 1;
    const int quad = lane >> 4, lrow = lane & 15;

    // ---- N/P staging: wave stages rows [wave*32, wave*32+32) of each tile.
    // 8 rows per g2l instr (row = lane>>3), 4 instrs per tile per iter.
    // slot s = lane&7 of row r holds logical chunk s ^ (r&7)  (16B chunks).
    const int srow = lane >> 3;                                   // 0..7
    const int kch  = ((lane & 7) ^ srow) * 8;                     // elem offset
    const unsigned short* gN = Nbf + (size_t)(j0 + wave * 32 + srow) * DIM + kch;
    const unsigned short* gP = Pbf + (size_t)(j0 + wave * 32 + srow) * DIM + kch;
    unsigned short* lN = sN + (wave * 32) * BK;
    unsigned short* lP = sP + (wave * 32) * BK;

    // ---- A fragments, global-direct: lane reads 16B of row (wm*64+im*16+lrow)
    // at k-chunk (half*4+quad)*8 within the K-tile (same logical layout the
    // LDS path delivered).
    const unsigned short* aBase =
        Abf + (size_t)(i0 + wm * 64 + lrow) * DIM + quad * 8;

    // ---- B fragment read: logical chunk c = half*4+quad, physical c^(lrow&7)
    const int rsw0 = ((0 * 4 + quad) ^ (lrow & 7)) * 8;   // half 0
    const int rsw1 = ((1 * 4 + quad) ^ (lrow & 7)) * 8;   // half 1
    const unsigned short* pbn = sN + (wn * 64 + lrow) * BK;
    const unsigned short* pbp = sP + (wn * 64 + lrow) * BK;

    f32x4 accN[4][4], accP[4][4];
#pragma unroll
    for (int im = 0; im < 4; im++)
#pragma unroll
        for (int jn = 0; jn < 4; jn++) {
            accN[im][jn] = (f32x4)(0.0f);
            accP[im][jn] = (f32x4)(0.0f);
        }

    for (int kt = 0; kt < DIM; kt += BK) {
        __syncthreads();   // protect LDS from previous iteration's readers
#pragma unroll
        for (int g = 0; g < 4; g++) {
            g2l16(gN + (size_t)kt + g * 8 * DIM, lN + g * 8 * BK);
            g2l16(gP + (size_t)kt + g * 8 * DIM, lP + g * 8 * BK);
        }
        // issue half-0 A-frag loads; the staging drain below retires them too
        bf16x8 af0[4];
#pragma unroll
        for (int im = 0; im < 4; im++)
            af0[im] = *(const bf16x8*)(aBase + (size_t)im * 16 * DIM + kt);
        __syncthreads();   // drains vmcnt before LDS reads

        // ---- half 0
        bf16x8 bn_fr[4], bp_fr[4];
#pragma unroll
        for (int jn = 0; jn < 4; jn++) {
            bn_fr[jn] = *(const bf16x8*)(pbn + jn * 16 * BK + rsw0);
            bp_fr[jn] = *(const bf16x8*)(pbp + jn * 16 * BK + rsw0);
        }
        // issue half-1 A-frag loads early; consumed after half-0 MFMAs
        bf16x8 af1[4];
#pragma unroll
        for (int im = 0; im < 4; im++)
            af1[im] = *(const bf16x8*)(aBase + (size_t)im * 16 * DIM + kt + 32);
#pragma unroll
        for (int im = 0; im < 4; im++)
#pragma unroll
            for (int jn = 0; jn < 4; jn++) {
                accN[im][jn] = __builtin_amdgcn_mfma_f32_16x16x32_bf16(
                    af0[im], bn_fr[jn], accN[im][jn], 0, 0, 0);
                accP[im][jn] = __builtin_amdgcn_mfma_f32_16x16x32_bf16(
                    af0[im], bp_fr[jn], accP[im][jn], 0, 0, 0);
            }

        // ---- half 1
#pragma unroll
        for (int jn = 0; jn < 4; jn++) {
            bn_fr[jn] = *(const bf16x8*)(pbn + jn * 16 * BK + rsw1);
            bp_fr[jn] = *(const bf16x8*)(pbp + jn * 16 * BK + rsw1);
        }
#pragma unroll
        for (int im = 0; im < 4; im++)
#pragma unroll
            for (int jn = 0; jn < 4; jn++) {
                accN[im][jn] = __builtin_amdgcn_mfma_f32_16x16x32_bf16(
                    af1[im], bn_fr[jn], accN[im][jn], 0, 0, 0);
                accP[im][jn] = __builtin_amdgcn_mfma_f32_16x16x32_bf16(
                    af1[im], bp_fr[jn], accP[im][jn], 0, 0, 0);
            }
    }

    // epilogue: distances + masks + row reduce + atomics
    const float* __restrict__ base_a = stats + 0 * NB;
    const float* __restrict__ cn_v   = stats + 1 * NB;
    const float* __restrict__ cp_v   = stats + 2 * NB;
    const float* __restrict__ d_ap   = stats + 3 * NB;
    const float* __restrict__ d_an   = stats + 4 * NB;
    unsigned* __restrict__ hard_n = ((unsigned*)stats) + 5 * NB;
    unsigned* __restrict__ hard_p = ((unsigned*)stats) + 6 * NB;

#pragma unroll
    for (int im = 0; im < 4; im++) {
#pragma unroll
        for (int r = 0; r < 4; r++) {
            const int gi = i0 + wm * 64 + im * 16 + quad * 4 + r;
            const float cutN = d_ap[gi];
            const float cutP = d_an[gi];
            const float bi   = base_a[gi];
            float bestN = 0.0f;
            float bestP = __uint_as_float(0x7f800000u);
#pragma unroll
            for (int jn = 0; jn < 4; jn++) {
                const int gj = j0 + wn * 64 + jn * 16 + lrow;
                const float dN = sqrtf(fmaxf(bi + cn_v[gj] - 2.0f * accN[im][jn][r], 0.0f));
                const float dP = sqrtf(fmaxf(bi + cp_v[gj] - 2.0f * accP[im][jn][r], 0.0f));
                if (dN < cutN && dN > bestN) bestN = dN;
                if (dP > cutP && dP < bestP) bestP = dP;
            }
#pragma unroll
            for (int m = 1; m < 16; m <<= 1) {
                bestN = fmaxf(bestN, __shfl_xor(bestN, m));
                bestP = fminf(bestP, __shfl_xor(bestP, m));
            }
            if (lrow == 0) {
                const unsigned bn_ = __float_as_uint(bestN);
                const unsigned bp_ = __float_as_uint(bestP);
                if (bn_ != 0u)          atomicMax(hard_n + gi, bn_);
                if (bp_ != 0x7f800000u) atomicMin(hard_p + gi, bp_);
            }
        }
    }
}

__global__ __launch_bounds__(1024) void finalize_kernel(
    const float* __restrict__ stats, float* __restrict__ out)
{
    const unsigned* hard_n = ((const unsigned*)stats) + 5 * NB;
    const unsigned* hard_p = ((const unsigned*)stats) + 6 * NB;
    const float*    d_ap   = stats + 3 * NB;
    const int t = threadIdx.x;
    const int wave = t >> 6, lane = t & 63;
    __shared__ float pn[16], pp[16];
    __shared__ float s_dan, s_dpp;

    float sn = 0.0f, sp = 0.0f;
    for (int i = t; i < NB; i += 1024) {
        sn += __uint_as_float(hard_n[i]);
        const unsigned hp = hard_p[i];
        if (hp != 0x7f800000u) sp += __uint_as_float(hp);
    }
#pragma unroll
    for (int m = 32; m >= 1; m >>= 1) {
        sn += __shfl_xor(sn, m);
        sp += __shfl_xor(sp, m);
    }
    if (lane == 0) { pn[wave] = sn; pp[wave] = sp; }
    __syncthreads();
    if (t == 0) {
        float an = 0.0f, ap = 0.0f;
#pragma unroll
        for (int w = 0; w < 16; w++) { an += pn[w]; ap += pp[w]; }
        s_dan = an / (float)NB;
        s_dpp = ap / (float)NB;
    }
    __syncthreads();
    const float dan = s_dan, dpp = s_dpp;

    float accv = 0.0f;
    for (int i = t; i < NB; i += 1024)
        accv += fmaxf(d_ap[i] - 0.5f * dpp - 0.5f * dan + 1.0f, 0.0f);
#pragma unroll
    for (int m = 32; m >= 1; m >>= 1) accv += __shfl_xor(accv, m);
    if (lane == 0) pn[wave] = accv;
    __syncthreads();
    if (t == 0) {
        float s = 0.0f;
#pragma unroll
        for (int w = 0; w < 16; w++) s += pn[w];
        out[0] = s / (float)NB;
    }
}

extern "C" void kernel_launch(void* const* d_in, const int* in_sizes, int n_in,
                              void* d_out, int out_size, void* d_ws, size_t ws_size,
                              hipStream_t stream) {
    const float* a = (const float*)d_in[0];
    const float* p = (const float*)d_in[1];
    const float* n = (const float*)d_in[2];
    float* out = (float*)d_out;

    // ws layout: abf | pbf | nbf | stats(7*NB floats)  => ~25.3 MB
    unsigned short* abf = (unsigned short*)d_ws;
    unsigned short* pbf = abf + (size_t)NB * DIM;
    unsigned short* nbf = pbf + (size_t)NB * DIM;
    float* stats = (float*)(nbf + (size_t)NB * DIM);

    row_stats_kernel<<<NB / 4, 256, 0, stream>>>(a, p, n, abf, pbf, nbf, stats);

    dim3 grid(NB / BM, NB / BM);
    gemm_mask_kernel<<<grid, 256, 0, stream>>>(abf, nbf, pbf, stats);

    finalize_kernel<<<1, 1024, 0, stream>>>(stats, out);
}

// Round 7
// 208.929 us; speedup vs baseline: 1.7889x; 1.7889x over previous
//
#include <hip/hip_runtime.h>

// ---------------------------------------------------------------------------
// TripletLossWithHardMining  (B=4096, D=1024, fp32 in, fp32 scalar out)
//
//  K1 row_stats : wave-per-row; per-row constants; d_ap, d_an_row; bf16
//                 copies of a,p,n; init hard slots.
//  K2 gemm_mask : R11 = R10 A-direct with the SPILL REMOVED.
//                 R10 failed because launch_bounds(256,3) capped regs at ~170
//                 vs ~212 demand -> acc spilled to scratch (WRITE_SIZE 398 MB,
//                 VGPR_Count 84, MfmaUtil 6.5). R11: launch_bounds(256,2)
//                 (2 blocks/CU, same as R0) -> ~220 regs fit, no spill.
//                 A-fragments load global->VGPR directly (absmax 0.0 in R10
//                 proved the layout); af0+af1 both issued BEFORE the staging
//                 barrier so its implicit vmcnt(0) drain covers their latency.
//                 LDS now stages only N,P: per block-K-tile reads 96->64 KB,
//                 writes 48->32 KB (-33% LDS-pipe traffic) -- the single
//                 variable vs R0's proven 96.7us structure.
//  K3 finalize  : d_an = mean(hard_n), d_pp = mean(hard_p, inf->0),
//                 loss = mean(relu(d_ap - 0.5*d_pp - 0.5*d_an + 1)).
//
//  Dead-ends (MfmaUtil pinned 24-29 across ALL -> LDS-traffic theory):
//   R4 barrier-free per-wave vmcnt(4):        184us, 15%
//   R5 fused 256x128 8-phase + vmcnt(0)/tile: 104us, 27%
//   R6 fused 256x128 4-phase counted:         107us, 26%
//   R7 unfused 128^2 2-barrier, 3 blk/CU:     104us, 27%
//   R9 unfused 256^2 k-half counted vmcnt(4): 117us, 24%
//   R10 A-direct + launch_bounds(256,3):      426us gemm -- REG SPILL, not a
//       test of A-direct (WRITE_SIZE 398MB scratch). Fixed here.
// ---------------------------------------------------------------------------

#define NB 4096
#define DIM 1024
#define EPSF 1e-6f
#define D_EPS2 (1024.0f * 1e-6f * 1e-6f)

#define BM 128           // block tile (rows and cols)
#define BK 64            // k-tile (bf16 elems) -> 128 B rows, unpadded

typedef __bf16  bf16x8 __attribute__((ext_vector_type(8)));
typedef float   f32x4  __attribute__((ext_vector_type(4)));

__device__ __forceinline__ unsigned short f2bf(float x) {
    unsigned u = __float_as_uint(x);
    u += 0x7FFFu + ((u >> 16) & 1u);   // round-to-nearest-even
    return (unsigned short)(u >> 16);
}

// async 16B/lane global->LDS; lds base wave-uniform, data lands at base+lane*16
__device__ __forceinline__ void g2l16(const unsigned short* g, unsigned short* l) {
    __builtin_amdgcn_global_load_lds(
        (const __attribute__((address_space(1))) unsigned int*)g,
        (__attribute__((address_space(3))) unsigned int*)l, 16, 0, 0);
}

// stats layout (NB-float slots):
// 0: base_a[i] = |a_i|^2 + 2e*sum_a + D*e^2
// 1: cn[j]     = |n_j|^2 - 2e*sum_n
// 2: cp[j]     = |p_j|^2 - 2e*sum_p
// 3: d_ap   4: d_an_row   5: hard_n bits   6: hard_p bits

// wave-per-row: 1024 blocks x 4 waves; lane handles 4 float4 chunks per matrix
__global__ __launch_bounds__(256) void row_stats_kernel(
    const float* __restrict__ a, const float* __restrict__ p,
    const float* __restrict__ n,
    unsigned short* __restrict__ abf, unsigned short* __restrict__ pbf,
    unsigned short* __restrict__ nbf, float* __restrict__ stats)
{
    const int t    = threadIdx.x;
    const int wave = t >> 6, lane = t & 63;
    const int row  = blockIdx.x * 4 + wave;
    const size_t base = (size_t)row * DIM;

    const float4* a4 = (const float4*)(a + base);
    const float4* p4 = (const float4*)(p + base);
    const float4* n4 = (const float4*)(n + base);

    float v[8] = {0,0,0,0,0,0,0,0};   // sa qa sp qp sn qn dap2 dan2
#pragma unroll
    for (int c = 0; c < 4; c++) {
        const int idx = c * 64 + lane;
        const float4 va = a4[idx];
        const float4 vp = p4[idx];
        const float4 vn = n4[idx];
        const float fa[4] = {va.x, va.y, va.z, va.w};
        const float fp[4] = {vp.x, vp.y, vp.z, vp.w};
        const float fn[4] = {vn.x, vn.y, vn.z, vn.w};
#pragma unroll
        for (int e = 0; e < 4; e++) {
            v[0] += fa[e];           v[1] += fa[e] * fa[e];
            v[2] += fp[e];           v[3] += fp[e] * fp[e];
            v[4] += fn[e];           v[5] += fn[e] * fn[e];
            float dp = fa[e] - fp[e] + EPSF;  v[6] += dp * dp;
            float dn = fa[e] - fn[e] + EPSF;  v[7] += dn * dn;
        }
        ushort4 ba, bp, bn;
        ba.x = f2bf(fa[0]); ba.y = f2bf(fa[1]); ba.z = f2bf(fa[2]); ba.w = f2bf(fa[3]);
        bp.x = f2bf(fp[0]); bp.y = f2bf(fp[1]); bp.z = f2bf(fp[2]); bp.w = f2bf(fp[3]);
        bn.x = f2bf(fn[0]); bn.y = f2bf(fn[1]); bn.z = f2bf(fn[2]); bn.w = f2bf(fn[3]);
        ((ushort4*)(abf + base))[idx] = ba;
        ((ushort4*)(pbf + base))[idx] = bp;
        ((ushort4*)(nbf + base))[idx] = bn;
    }

#pragma unroll
    for (int m = 32; m >= 1; m >>= 1)
#pragma unroll
        for (int q = 0; q < 8; q++) v[q] += __shfl_xor(v[q], m);

    if (lane == 0) {
        stats[0 * NB + row] = v[1] + 2.0f * EPSF * v[0] + D_EPS2;  // base_a
        stats[1 * NB + row] = v[5] - 2.0f * EPSF * v[4];           // cn
        stats[2 * NB + row] = v[3] - 2.0f * EPSF * v[2];           // cp
        stats[3 * NB + row] = sqrtf(v[6]);                         // d_ap
        stats[4 * NB + row] = sqrtf(v[7]);                         // d_an_row
        ((unsigned*)stats)[5 * NB + row] = 0u;                     // hard_n
        ((unsigned*)stats)[6 * NB + row] = 0x7f800000u;            // hard_p
    }
}

// grid (32, 32): each block computes both A.N^T and A.P^T for its tile.
// A-fragments come straight from global (L1/L2-served); LDS holds only N, P.
__global__ __launch_bounds__(256, 2) void gemm_mask_kernel(
    const unsigned short* __restrict__ Abf,
    const unsigned short* __restrict__ Nbf,
    const unsigned short* __restrict__ Pbf,
    float* __restrict__ stats)
{
    const int i0 = blockIdx.x * BM;
    const int j0 = blockIdx.y * BM;

    __shared__ unsigned short sN[BM * BK];   // 16 KB
    __shared__ unsigned short sP[BM * BK];   // 16 KB -> 32 KB total

    const int t    = threadIdx.x;
    const int wave = t >> 6, lane = t & 63;
    const int wm   = wave >> 1, wn = wave & 1;
    const int quad = lane >> 4, lrow = lane & 15;

    // ---- N/P staging: wave stages rows [wave*32, wave*32+32) of each tile.
    // 8 rows per g2l instr (row = lane>>3), 4 instrs per tile per iter.
    // slot s = lane&7 of row r holds logical chunk s ^ (r&7)  (16B chunks).
    const int srow = lane >> 3;                                   // 0..7
    const int kch  = ((lane & 7) ^ srow) * 8;                     // elem offset
    const unsigned short* gN = Nbf + (size_t)(j0 + wave * 32 + srow) * DIM + kch;
    const unsigned short* gP = Pbf + (size_t)(j0 + wave * 32 + srow) * DIM + kch;
    unsigned short* lN = sN + (wave * 32) * BK;
    unsigned short* lP = sP + (wave * 32) * BK;

    // ---- A fragments, global-direct: lane reads 16B of row (wm*64+im*16+lrow)
    // at k-chunk (half*4+quad)*8 within the K-tile (same logical layout the
    // LDS path delivered). Verified: R10 absmax 0.0.
    const unsigned short* aBase =
        Abf + (size_t)(i0 + wm * 64 + lrow) * DIM + quad * 8;

    // ---- B fragment read: logical chunk c = half*4+quad, physical c^(lrow&7)
    const int rsw0 = ((0 * 4 + quad) ^ (lrow & 7)) * 8;   // half 0
    const int rsw1 = ((1 * 4 + quad) ^ (lrow & 7)) * 8;   // half 1
    const unsigned short* pbn = sN + (wn * 64 + lrow) * BK;
    const unsigned short* pbp = sP + (wn * 64 + lrow) * BK;

    f32x4 accN[4][4], accP[4][4];
#pragma unroll
    for (int im = 0; im < 4; im++)
#pragma unroll
        for (int jn = 0; jn < 4; jn++) {
            accN[im][jn] = (f32x4)(0.0f);
            accP[im][jn] = (f32x4)(0.0f);
        }

    for (int kt = 0; kt < DIM; kt += BK) {
        __syncthreads();   // protect LDS from previous iteration's readers
#pragma unroll
        for (int g = 0; g < 4; g++) {
            g2l16(gN + (size_t)kt + g * 8 * DIM, lN + g * 8 * BK);
            g2l16(gP + (size_t)kt + g * 8 * DIM, lP + g * 8 * BK);
        }
        // issue BOTH A half-fragments now; the barrier's implicit vmcnt(0)
        // drain (needed for the g2l staging anyway) retires them for free.
        bf16x8 af0[4], af1[4];
#pragma unroll
        for (int im = 0; im < 4; im++) {
            af0[im] = *(const bf16x8*)(aBase + (size_t)im * 16 * DIM + kt);
            af1[im] = *(const bf16x8*)(aBase + (size_t)im * 16 * DIM + kt + 32);
        }
        __syncthreads();   // drains vmcnt before LDS reads

        // ---- half 0
        bf16x8 bn_fr[4], bp_fr[4];
#pragma unroll
        for (int jn = 0; jn < 4; jn++) {
            bn_fr[jn] = *(const bf16x8*)(pbn + jn * 16 * BK + rsw0);
            bp_fr[jn] = *(const bf16x8*)(pbp + jn * 16 * BK + rsw0);
        }
#pragma unroll
        for (int im = 0; im < 4; im++)
#pragma unroll
            for (int jn = 0; jn < 4; jn++) {
                accN[im][jn] = __builtin_amdgcn_mfma_f32_16x16x32_bf16(
                    af0[im], bn_fr[jn], accN[im][jn], 0, 0, 0);
                accP[im][jn] = __builtin_amdgcn_mfma_f32_16x16x32_bf16(
                    af0[im], bp_fr[jn], accP[im][jn], 0, 0, 0);
            }

        // ---- half 1
#pragma unroll
        for (int jn = 0; jn < 4; jn++) {
            bn_fr[jn] = *(const bf16x8*)(pbn + jn * 16 * BK + rsw1);
            bp_fr[jn] = *(const bf16x8*)(pbp + jn * 16 * BK + rsw1);
        }
#pragma unroll
        for (int im = 0; im < 4; im++)
#pragma unroll
            for (int jn = 0; jn < 4; jn++) {
                accN[im][jn] = __builtin_amdgcn_mfma_f32_16x16x32_bf16(
                    af1[im], bn_fr[jn], accN[im][jn], 0, 0, 0);
                accP[im][jn] = __builtin_amdgcn_mfma_f32_16x16x32_bf16(
                    af1[im], bp_fr[jn], accP[im][jn], 0, 0, 0);
            }
    }

    // epilogue: distances + masks + row reduce + atomics
    const float* __restrict__ base_a = stats + 0 * NB;
    const float* __restrict__ cn_v   = stats + 1 * NB;
    const float* __restrict__ cp_v   = stats + 2 * NB;
    const float* __restrict__ d_ap   = stats + 3 * NB;
    const float* __restrict__ d_an   = stats + 4 * NB;
    unsigned* __restrict__ hard_n = ((unsigned*)stats) + 5 * NB;
    unsigned* __restrict__ hard_p = ((unsigned*)stats) + 6 * NB;

#pragma unroll
    for (int im = 0; im < 4; im++) {
#pragma unroll
        for (int r = 0; r < 4; r++) {
            const int gi = i0 + wm * 64 + im * 16 + quad * 4 + r;
            const float cutN = d_ap[gi];
            const float cutP = d_an[gi];
            const float bi   = base_a[gi];
            float bestN = 0.0f;
            float bestP = __uint_as_float(0x7f800000u);
#pragma unroll
            for (int jn = 0; jn < 4; jn++) {
                const int gj = j0 + wn * 64 + jn * 16 + lrow;
                const float dN = sqrtf(fmaxf(bi + cn_v[gj] - 2.0f * accN[im][jn][r], 0.0f));
                const float dP = sqrtf(fmaxf(bi + cp_v[gj] - 2.0f * accP[im][jn][r], 0.0f));
                if (dN < cutN && dN > bestN) bestN = dN;
                if (dP > cutP && dP < bestP) bestP = dP;
            }
#pragma unroll
            for (int m = 1; m < 16; m <<= 1) {
                bestN = fmaxf(bestN, __shfl_xor(bestN, m));
                bestP = fminf(bestP, __shfl_xor(bestP, m));
            }
            if (lrow == 0) {
                const unsigned bn_ = __float_as_uint(bestN);
                const unsigned bp_ = __float_as_uint(bestP);
                if (bn_ != 0u)          atomicMax(hard_n + gi, bn_);
                if (bp_ != 0x7f800000u) atomicMin(hard_p + gi, bp_);
            }
        }
    }
}

__global__ __launch_bounds__(1024) void finalize_kernel(
    const float* __restrict__ stats, float* __restrict__ out)
{
    const unsigned* hard_n = ((const unsigned*)stats) + 5 * NB;
    const unsigned* hard_p = ((const unsigned*)stats) + 6 * NB;
    const float*    d_ap   = stats + 3 * NB;
    const int t = threadIdx.x;
    const int wave = t >> 6, lane = t & 63;
    __shared__ float pn[16], pp[16];
    __shared__ float s_dan, s_dpp;

    float sn = 0.0f, sp = 0.0f;
    for (int i = t; i < NB; i += 1024) {
        sn += __uint_as_float(hard_n[i]);
        const unsigned hp = hard_p[i];
        if (hp != 0x7f800000u) sp += __uint_as_float(hp);
    }
#pragma unroll
    for (int m = 32; m >= 1; m >>= 1) {
        sn += __shfl_xor(sn, m);
        sp += __shfl_xor(sp, m);
    }
    if (lane == 0) { pn[wave] = sn; pp[wave] = sp; }
    __syncthreads();
    if (t == 0) {
        float an = 0.0f, ap = 0.0f;
#pragma unroll
        for (int w = 0; w < 16; w++) { an += pn[w]; ap += pp[w]; }
        s_dan = an / (float)NB;
        s_dpp = ap / (float)NB;
    }
    __syncthreads();
    const float dan = s_dan, dpp = s_dpp;

    float accv = 0.0f;
    for (int i = t; i < NB; i += 1024)
        accv += fmaxf(d_ap[i] - 0.5f * dpp - 0.5f * dan + 1.0f, 0.0f);
#pragma unroll
    for (int m = 32; m >= 1; m >>= 1) accv += __shfl_xor(accv, m);
    if (lane == 0) pn[wave] = accv;
    __syncthreads();
    if (t == 0) {
        float s = 0.0f;
#pragma unroll
        for (int w = 0; w < 16; w++) s += pn[w];
        out[0] = s / (float)NB;
    }
}

extern "C" void kernel_launch(void* const* d_in, const int* in_sizes, int n_in,
                              void* d_out, int out_size, void* d_ws, size_t ws_size,
                              hipStream_t stream) {
    const float* a = (const float*)d_in[0];
    const float* p = (const float*)d_in[1];
    const float* n = (const float*)d_in[2];
    float* out = (float*)d_out;

    // ws layout: abf | pbf | nbf | stats(7*NB floats)  => ~25.3 MB
    unsigned short* abf = (unsigned short*)d_ws;
    unsigned short* pbf = abf + (size_t)NB * DIM;
    unsigned short* nbf = pbf + (size_t)NB * DIM;
    float* stats = (float*)(nbf + (size_t)NB * DIM);

    row_stats_kernel<<<NB / 4, 256, 0, stream>>>(a, p, n, abf, pbf, nbf, stats);

    dim3 grid(NB / BM, NB / BM);
    gemm_mask_kernel<<<grid, 256, 0, stream>>>(abf, nbf, pbf, stats);

    finalize_kernel<<<1, 1024, 0, stream>>>(stats, out);
}